// Round 6
// baseline (372.762 us; speedup 1.0000x reference)
//
#include <hip/hip_runtime.h>

// out[b,o] = sum_e ( relu(relu(x[b,e,:]@W1[e]+b1[e])@W2[e]+b2[e]) @ W3[e] + b3[e] )
// E=16, DIN=128, H=512, DOUT=64, B=8192.  94.5 GFLOP.
//
// R11: occupancy fix, take 2. Diagnosis: occupancy has been 23% (2 waves/SIMD)
// in EVERY round regardless of LDS, because VGPR_Count (104-128) EXCLUDES the
// MFMA accumulators (AGPRs, unified file on gfx950): total ~170-240 regs/wave
// -> 2 waves/SIMD. Only R6 (VGPR 64, spilled) ever showed 44%.
// Fix: 1024-thread / 16-wave blocks; per-wave L1/L2 tile 64x32 (n: 4->2):
//   acc 32 regs (was 64), afr double-buf 32, bfr triple-buf 24 -> ~127 total.
//   __launch_bounds__(1024,1) = hard cap 128 = 4 waves/SIMD = 2x occupancy.
// L3: 16 waves = (2 mp) x (4 n3) x (2 kh K-halves); b3f[8] per wave (its half).
//   Only kh=0 waves add b3 bias (else double-count). Atomics: both kh halves
//   add -> 2x R9's count but still EG-accumulated (/4 vs R7).
// sX staging RESTORED (R10's direct-global X cost +17MB FETCH for nothing);
//   X(e+1) prefetched into 2 regs during L3 (8 VGPR, not R9's full-state).
// Kept: EG=4, swapped-operand epilogue (b64 LDS writes), bias-in-acc,
//   XCD expert pinning, setprio, folded memset.

#define NE   16
#define NDIN 128
#define NH   512
#define NDO  64
#define NB   8192
#define EG   4

using bf16x8 = __attribute__((ext_vector_type(8))) __bf16;
using bf16x4 = __attribute__((ext_vector_type(4))) __bf16;
using f32x4  = __attribute__((ext_vector_type(4))) float;

__device__ __forceinline__ unsigned short f2bf(float f) {
    union { float f; unsigned u; } v; v.f = f;
    unsigned r = v.u + 0x7FFFu + ((v.u >> 16) & 1u);   // RNE
    return (unsigned short)(r >> 16);
}

// compiler-fusable bf16 conversion (emits v_cvt_pk_bf16_f32 pairs)
__device__ __forceinline__ bf16x8 cvt8(float4 a, float4 b) {
    bf16x8 r;
    r[0] = (__bf16)a.x; r[1] = (__bf16)a.y; r[2] = (__bf16)a.z; r[3] = (__bf16)a.w;
    r[4] = (__bf16)b.x; r[5] = (__bf16)b.y; r[6] = (__bf16)b.z; r[7] = (__bf16)b.w;
    return r;
}

// Swizzled index (ushort units): 16B granules XOR'd by row&15 (0 conflicts measured).
__device__ __forceinline__ int shidx(int m, int n) {          // H tile, stride 512
    return m * NH + (((n >> 3) ^ (m & 15)) << 3) + (n & 7);
}
__device__ __forceinline__ int shx(int m, int n) {            // X tile, stride 128
    return m * NDIN + ((((n >> 3) ^ (m & 15)) & 15) << 3) + (n & 7);
}

// ---------------- merged prep: fp32 [e][R][C] -> bf16 [e][C][R]  (+ out zeroing) ----------------
__global__ __launch_bounds__(256) void prep_weights(
    const float* __restrict__ W1, const float* __restrict__ W2, const float* __restrict__ W3,
    unsigned short* __restrict__ W1t, unsigned short* __restrict__ W2t, unsigned short* __restrict__ W3t,
    float* __restrict__ out)
{
    __shared__ float tile[64][65];
    const int t = blockIdx.x, e = blockIdx.y;
    // fold the output memset into this dispatch: 64 blocks x 32KB = 2MB
    if (e == 0 && t < 64) {
        float4* oz = (float4*)(out + (size_t)t * 8192);
        const float4 z = {0.f, 0.f, 0.f, 0.f};
#pragma unroll
        for (int i = 0; i < 8; ++i) oz[i * 256 + threadIdx.x] = z;
    }
    const float* src; unsigned short* dst; int R, C, tr, tc;
    if (t < 16)      { src = W1; dst = W1t; R = NDIN; C = NH;  tr = t >> 3;        tc = t & 7;  }
    else if (t < 80) { src = W2; dst = W2t; R = NH;   C = NH;  tr = (t - 16) >> 3; tc = (t - 16) & 7; }
    else             { src = W3; dst = W3t; R = NH;   C = NDO; tr = t - 80;        tc = 0;      }
    const int r0 = tr * 64, c0 = tc * 64;
    const float* s = src + (size_t)e * R * C;
    unsigned short* d = dst + (size_t)e * R * C;
    const int tt = threadIdx.x;
#pragma unroll
    for (int i = 0; i < 4; ++i) {
        int f = i * 256 + tt;
        int r = f >> 4, c4 = (f & 15) * 4;
        const float4 v = *(const float4*)(s + (size_t)(r0 + r) * C + c0 + c4);
        tile[r][c4 + 0] = v.x; tile[r][c4 + 1] = v.y;
        tile[r][c4 + 2] = v.z; tile[r][c4 + 3] = v.w;
    }
    __syncthreads();
#pragma unroll
    for (int i = 0; i < 4; ++i) {
        int f = i * 256 + tt;
        int cc = f >> 4, rb = (f & 15) * 4;
        ushort4 o;
        o.x = f2bf(tile[rb + 0][cc]);
        o.y = f2bf(tile[rb + 1][cc]);
        o.z = f2bf(tile[rb + 2][cc]);
        o.w = f2bf(tile[rb + 3][cc]);
        *(ushort4*)(d + (size_t)(c0 + cc) * R + r0 + rb) = o;
    }
}

// ---------------- fused 3-layer expert MLP: 4 experts x 64 rows per 16-wave WG ----------------
__global__ __launch_bounds__(1024, 1) void moe_fused(
    const float* __restrict__ x,            // [B][E][DIN]
    const float* __restrict__ b1,           // [E][H]
    const float* __restrict__ b2,           // [E][H]
    const float* __restrict__ b3,           // [E][DOUT]
    const unsigned short* __restrict__ W1t, // [E][H][DIN]  bf16
    const unsigned short* __restrict__ W2t, // [E][H][H]    bf16
    const unsigned short* __restrict__ W3t, // [E][DOUT][H] bf16
    float* __restrict__ out)                // [B][DOUT]  (pre-zeroed by prep)
{
    __shared__ unsigned short sMem[64 * NDIN + 64 * NH];  // 16KB X + 64KB H = 80KB
    unsigned short* sX = sMem;
    unsigned short* sH = sMem + 64 * NDIN;

    const int tid  = threadIdx.x;
    const int wave = tid >> 6;            // 0..15
    const int lane = tid & 63;
    const int q    = lane >> 4;
    const int l16  = lane & 15;
    const int hi2  = l16 >> 2;
    const int lo2  = l16 & 3;
    const int qe   = (q ^ lo2) * 8;       // swizzled in-granule element offset

    // grid 512: xcd = lin&7; e-group = xcd>>1 (4 experts pinned per XCD pair);
    // row-tile = ((lin>>3)<<1)|(xcd&1) in 0..127.
    const int lin = blockIdx.x;
    const int xcd = lin & 7;
    const int eg  = xcd >> 1;
    const int rt  = ((lin >> 3) << 1) | (xcd & 1);
    const int b0  = rt << 6;
    const int nb  = wave * 32;            // 32 H-cols per wave in L1/L2

    // per-wave LDS A-frag base offsets (elements);  read addr = base + ((kt^hi2)<<5)
    int aH[4], aX[4];
#pragma unroll
    for (int m = 0; m < 4; ++m) {
        aH[m] = (m * 16 + l16) * NH   + qe;
        aX[m] = (m * 16 + l16) * NDIN + qe;
    }
    const int r0 = tid >> 4, c8 = (tid & 15) * 8;   // x staging coords (1024 thr = 64x16)

    // L3 wave mapping: (2 mp) x (4 n3) x (2 kh K-halves)
    const int n3 = wave & 3, mp = (wave >> 2) & 1, kh = wave >> 3;
    int a3[2];
#pragma unroll
    for (int i = 0; i < 2; ++i) a3[i] = ((2 * mp + i) * 16 + l16) * NH + qe;

    f32x4 oacc[2];
    oacc[0] = {0.f, 0.f, 0.f, 0.f}; oacc[1] = {0.f, 0.f, 0.f, 0.f};
    float bacc = 0.f;

    bf16x8 afr[2][4];   // LDS A-frags, lookahead-1
    bf16x8 bfr[3][2];   // weight B-frags, lookahead-2

    // prologue: X(e0) into regs
    float4 xu0, xu1;
    {
        const int e0 = eg * EG;
        const float* p = x + ((size_t)(b0 + r0) * NE + e0) * NDIN + c8;
        xu0 = *(const float4*)p; xu1 = *(const float4*)(p + 4);
    }

#pragma unroll 1
    for (int ei = 0; ei < EG; ++ei) {
        const int e = eg * EG + ei;

        // stage sX(e) from prefetched regs; issue W1 s=0,1 + b1 (hide under barrier)
        *(bf16x8*)&sX[shx(r0, c8)] = cvt8(xu0, xu1);
        const unsigned short* wb1[2];
#pragma unroll
        for (int n = 0; n < 2; ++n)
            wb1[n] = W1t + (size_t)e * NH * NDIN + (size_t)(nb + n * 16 + l16) * NDIN + q * 8;
#pragma unroll
        for (int s = 0; s < 2; ++s)
#pragma unroll
            for (int n = 0; n < 2; ++n)
                bfr[s][n] = *(const bf16x8*)(wb1[n] + s * 32);
        float4 b1q[2];
#pragma unroll
        for (int n = 0; n < 2; ++n)
            b1q[n] = *(const float4*)(b1 + e * NH + nb + n * 16 + q * 4);

        __syncthreads();   // A: sX visible; previous expert's L3 sH reads done

        // ---------------- layer 1: acc = X @ W1 + b1, 4 kt ----------------
        f32x4 acc[4][2];
#pragma unroll
        for (int n = 0; n < 2; ++n) {
            const f32x4 bi = {b1q[n].x, b1q[n].y, b1q[n].z, b1q[n].w};
#pragma unroll
            for (int m = 0; m < 4; ++m) acc[m][n] = bi;
        }
#pragma unroll
        for (int m = 0; m < 4; ++m)
            afr[0][m] = *(const bf16x8*)&sX[aX[m] + (((0 ^ hi2) & 3) << 5)];

#pragma unroll
        for (int kt = 0; kt < 4; ++kt) {
            if (kt < 3)
#pragma unroll
                for (int m = 0; m < 4; ++m)
                    afr[(kt + 1) & 1][m] = *(const bf16x8*)&sX[aX[m] + ((((kt + 1) ^ hi2) & 3) << 5)];
            if (kt < 2)
#pragma unroll
                for (int n = 0; n < 2; ++n)
                    bfr[(kt + 2) % 3][n] = *(const bf16x8*)(wb1[n] + (kt + 2) * 32);
            __builtin_amdgcn_s_setprio(1);
#pragma unroll
            for (int m = 0; m < 4; ++m)
#pragma unroll
                for (int n = 0; n < 2; ++n)
                    acc[m][n] = __builtin_amdgcn_mfma_f32_16x16x32_bf16(
                        bfr[kt % 3][n], afr[kt & 1][m], acc[m][n], 0, 0, 0);
            __builtin_amdgcn_s_setprio(0);
        }

        // W2 prologue + b2 in flight over the H1 epilogue + barrier
        const unsigned short* wb2[2];
#pragma unroll
        for (int n = 0; n < 2; ++n)
            wb2[n] = W2t + (size_t)e * NH * NH + (size_t)(nb + n * 16 + l16) * NH + q * 8;
#pragma unroll
        for (int s = 0; s < 2; ++s)
#pragma unroll
            for (int n = 0; n < 2; ++n)
                bfr[s][n] = *(const bf16x8*)(wb2[n] + s * 32);
        float4 b2q[2];
#pragma unroll
        for (int n = 0; n < 2; ++n)
            b2q[n] = *(const float4*)(b2 + e * NH + nb + n * 16 + q * 4);

        // H1 epilogue: per (m,n) 4 consecutive hcols at one row -> one ds_write_b64
#pragma unroll
        for (int n = 0; n < 2; ++n) {
            const int c0 = nb + n * 16 + q * 4;
#pragma unroll
            for (int m = 0; m < 4; ++m) {
                bf16x4 pk;
#pragma unroll
                for (int r = 0; r < 4; ++r) pk[r] = (__bf16)fmaxf(acc[m][n][r], 0.f);
                *(bf16x4*)&sH[shidx(m * 16 + l16, c0)] = pk;
            }
        }
        __syncthreads();   // B: H1 visible

        // ---------------- layer 2: acc2 = H1 @ W2 (+b2), 16 kt ----------------
        f32x4 acc2[4][2];
#pragma unroll
        for (int n = 0; n < 2; ++n) {
            const f32x4 bi = {b2q[n].x, b2q[n].y, b2q[n].z, b2q[n].w};
#pragma unroll
            for (int m = 0; m < 4; ++m) acc2[m][n] = bi;
        }
#pragma unroll
        for (int m = 0; m < 4; ++m)
            afr[0][m] = *(const bf16x8*)&sH[aH[m] + (((0 ^ hi2)) << 5)];

#pragma unroll
        for (int kt = 0; kt < 16; ++kt) {
            if (kt < 15)
#pragma unroll
                for (int m = 0; m < 4; ++m)
                    afr[(kt + 1) & 1][m] = *(const bf16x8*)&sH[aH[m] + ((((kt + 1) ^ hi2)) << 5)];
            if (kt < 14)
#pragma unroll
                for (int n = 0; n < 2; ++n)
                    bfr[(kt + 2) % 3][n] = *(const bf16x8*)(wb2[n] + (kt + 2) * 32);
            __builtin_amdgcn_s_setprio(1);
#pragma unroll
            for (int m = 0; m < 4; ++m)
#pragma unroll
                for (int n = 0; n < 2; ++n)
                    acc2[m][n] = __builtin_amdgcn_mfma_f32_16x16x32_bf16(
                        bfr[kt % 3][n], afr[kt & 1][m], acc2[m][n], 0, 0, 0);
            __builtin_amdgcn_s_setprio(0);
        }

        // W3(e) kh-half: 8 B3 frags + b3; X(e+1) prefetch (8 regs, wrap-discarded)
        const unsigned short* wb3 = W3t + (size_t)e * NDO * NH + (size_t)(n3 * 16 + l16) * NH + q * 8;
        bf16x8 b3f[8];
#pragma unroll
        for (int j = 0; j < 8; ++j) b3f[j] = *(const bf16x8*)(wb3 + (kh * 8 + j) * 32);
        const float b3v = b3[e * NDO + n3 * 16 + l16];
        {
            const int en = eg * EG + ((ei + 1) & (EG - 1));
            const float* p = x + ((size_t)(b0 + r0) * NE + en) * NDIN + c8;
            xu0 = *(const float4*)p; xu1 = *(const float4*)(p + 4);
        }

        __syncthreads();   // C: all L2 sH reads complete before overwrite

        // H2 epilogue
#pragma unroll
        for (int n = 0; n < 2; ++n) {
            const int c0 = nb + n * 16 + q * 4;
#pragma unroll
            for (int m = 0; m < 4; ++m) {
                bf16x4 pk;
#pragma unroll
                for (int r = 0; r < 4; ++r) pk[r] = (__bf16)fmaxf(acc2[m][n][r], 0.f);
                *(bf16x4*)&sH[shidx(m * 16 + l16, c0)] = pk;
            }
        }
        __syncthreads();   // D: H2 visible

        // ---------------- layer 3: oacc += H2[kh-half] @ W3 (A lookahead-3) ----------------
        bf16x8 a3f[4][2];
#pragma unroll
        for (int s = 0; s < 3; ++s)
#pragma unroll
            for (int i = 0; i < 2; ++i)
                a3f[s][i] = *(const bf16x8*)&sH[a3[i] + ((((kh * 8 + s) ^ hi2)) << 5)];

#pragma unroll
        for (int j = 0; j < 8; ++j) {
            const int kt = kh * 8 + j;
            if (j < 5) {
                const int pre = (j + 3) & 3;
#pragma unroll
                for (int i = 0; i < 2; ++i)
                    a3f[pre][i] = *(const bf16x8*)&sH[a3[i] + ((((kt + 3) ^ hi2)) << 5)];
            }
            __builtin_amdgcn_s_setprio(1);
#pragma unroll
            for (int i = 0; i < 2; ++i)
                oacc[i] = __builtin_amdgcn_mfma_f32_16x16x32_bf16(
                    a3f[j & 3][i], b3f[j], oacc[i], 0, 0, 0);
            __builtin_amdgcn_s_setprio(0);
        }
        bacc += kh ? 0.f : b3v;   // bias only from the kh=0 half (no double-count)
    }

    // final: 4-expert-accumulated contribution -> global fp32 atomics
#pragma unroll
    for (int i = 0; i < 2; ++i) {
        const int col = n3 * 16 + l16;
#pragma unroll
        for (int r = 0; r < 4; ++r) {
            const int row = b0 + (2 * mp + i) * 16 + q * 4 + r;
            unsafeAtomicAdd(out + (size_t)row * NDO + col, oacc[i][r] + bacc);
        }
    }
}

extern "C" void kernel_launch(void* const* d_in, const int* in_sizes, int n_in,
                              void* d_out, int out_size, void* d_ws, size_t ws_size,
                              hipStream_t stream) {
    const float* x  = (const float*)d_in[0];
    const float* W1 = (const float*)d_in[1];
    const float* b1 = (const float*)d_in[2];
    const float* W2 = (const float*)d_in[3];
    const float* b2 = (const float*)d_in[4];
    const float* W3 = (const float*)d_in[5];
    const float* b3 = (const float*)d_in[6];
    float* out = (float*)d_out;

    unsigned short* W1t = (unsigned short*)d_ws;            // [E][H][DIN]
    unsigned short* W2t = W1t + (size_t)NE * NH * NDIN;     // [E][H][H]
    unsigned short* W3t = W2t + (size_t)NE * NH * NH;       // [E][DOUT][H]

    prep_weights<<<dim3(88, NE), 256, 0, stream>>>(W1, W2, W3, W1t, W2t, W3t, out);
    moe_fused<<<dim3((NB / 64) * (NE / EG)), 1024, 0, stream>>>(x, b1, b2, b3, W1t, W2t, W3t, out);
}

// Round 7
// 290.529 us; speedup vs baseline: 1.2830x; 1.2830x over previous
//
#include <hip/hip_runtime.h>

// out[b,o] = sum_e ( relu(relu(x[b,e,:]@W1[e]+b1[e])@W2[e]+b2[e]) @ W3[e] + b3[e] )
// E=16, DIN=128, H=512, DOUT=64, B=8192.  94.5 GFLOP.
//
// R13 = R7-core (best, 208us) + EG=4 + double-buffered sH, no-spill discipline.
//  Commit to 2 waves/SIMD / 1 block/CU (R6/R11: >2 waves => guaranteed spill).
//  Attack the serial overhead of that regime instead:
//  (1) sH DOUBLE-BUFFER (sHA=L1 out, sHB=L2 out; LDS 16+64+64=144KB): barriers
//      drop to 2/expert (was 4-5).  WAR audit: each buffer's writer is >=1
//      barrier past its last reader (L2(e-1) ends before BAR-2(e-1) < H1epi(e);
//      L3(e-1) ends before BAR-1(e) < H2epi(e); L1(e) ends before BAR-1(e) <
//      sX(e+1) write).  Per CU: 2 blocks x 9 drains = 18 vs R7's 32.
//  (2) EG=4 experts/block (atomics /4, proven R10: WRITE 8.4MB); 4x fewer cold
//      prologues + atomic tails per CU.
//  (3) Spill discipline (R9 inverted): NO cross-expert W1/b1 prefetch (reload
//      at iter top, ~300cyc L2 hit); b3f[16] -> rotating b3f[8] (R10-proven);
//      X(e+1) prefetch = 16 regs held across one epilogue only. Peak ~216 regs.
//  (4) setprio dropped (R7-best had none; null for lockstep 1-block waves).
// Kept: swapped-operand MFMA epilogue (ds_write_b64), bias-in-acc, XCD expert
//   pinning (4 experts per XCD pair), launch_bounds(512,2), folded memset.

#define NE   16
#define NDIN 128
#define NH   512
#define NDO  64
#define NB   8192
#define EG   4

using bf16x8 = __attribute__((ext_vector_type(8))) __bf16;
using bf16x4 = __attribute__((ext_vector_type(4))) __bf16;
using f32x4  = __attribute__((ext_vector_type(4))) float;

__device__ __forceinline__ unsigned short f2bf(float f) {
    union { float f; unsigned u; } v; v.f = f;
    unsigned r = v.u + 0x7FFFu + ((v.u >> 16) & 1u);   // RNE
    return (unsigned short)(r >> 16);
}

// compiler-fusable bf16 conversion (emits v_cvt_pk_bf16_f32 pairs)
__device__ __forceinline__ bf16x8 cvt8(float4 a, float4 b) {
    bf16x8 r;
    r[0] = (__bf16)a.x; r[1] = (__bf16)a.y; r[2] = (__bf16)a.z; r[3] = (__bf16)a.w;
    r[4] = (__bf16)b.x; r[5] = (__bf16)b.y; r[6] = (__bf16)b.z; r[7] = (__bf16)b.w;
    return r;
}

// Swizzled index (ushort units): 16B granules XOR'd by row&15 (0 conflicts measured).
__device__ __forceinline__ int shidx(int m, int n) {          // H tile, stride 512
    return m * NH + (((n >> 3) ^ (m & 15)) << 3) + (n & 7);
}
__device__ __forceinline__ int shx(int m, int n) {            // X tile, stride 128
    return m * NDIN + ((((n >> 3) ^ (m & 15)) & 15) << 3) + (n & 7);
}

// ---------------- merged prep: fp32 [e][R][C] -> bf16 [e][C][R]  (+ out zeroing) ----------------
__global__ __launch_bounds__(256) void prep_weights(
    const float* __restrict__ W1, const float* __restrict__ W2, const float* __restrict__ W3,
    unsigned short* __restrict__ W1t, unsigned short* __restrict__ W2t, unsigned short* __restrict__ W3t,
    float* __restrict__ out)
{
    __shared__ float tile[64][65];
    const int t = blockIdx.x, e = blockIdx.y;
    // fold the output memset into this dispatch: 64 blocks x 32KB = 2MB
    if (e == 0 && t < 64) {
        float4* oz = (float4*)(out + (size_t)t * 8192);
        const float4 z = {0.f, 0.f, 0.f, 0.f};
#pragma unroll
        for (int i = 0; i < 8; ++i) oz[i * 256 + threadIdx.x] = z;
    }
    const float* src; unsigned short* dst; int R, C, tr, tc;
    if (t < 16)      { src = W1; dst = W1t; R = NDIN; C = NH;  tr = t >> 3;        tc = t & 7;  }
    else if (t < 80) { src = W2; dst = W2t; R = NH;   C = NH;  tr = (t - 16) >> 3; tc = (t - 16) & 7; }
    else             { src = W3; dst = W3t; R = NH;   C = NDO; tr = t - 80;        tc = 0;      }
    const int r0 = tr * 64, c0 = tc * 64;
    const float* s = src + (size_t)e * R * C;
    unsigned short* d = dst + (size_t)e * R * C;
    const int tt = threadIdx.x;
#pragma unroll
    for (int i = 0; i < 4; ++i) {
        int f = i * 256 + tt;
        int r = f >> 4, c4 = (f & 15) * 4;
        const float4 v = *(const float4*)(s + (size_t)(r0 + r) * C + c0 + c4);
        tile[r][c4 + 0] = v.x; tile[r][c4 + 1] = v.y;
        tile[r][c4 + 2] = v.z; tile[r][c4 + 3] = v.w;
    }
    __syncthreads();
#pragma unroll
    for (int i = 0; i < 4; ++i) {
        int f = i * 256 + tt;
        int cc = f >> 4, rb = (f & 15) * 4;
        ushort4 o;
        o.x = f2bf(tile[rb + 0][cc]);
        o.y = f2bf(tile[rb + 1][cc]);
        o.z = f2bf(tile[rb + 2][cc]);
        o.w = f2bf(tile[rb + 3][cc]);
        *(ushort4*)(d + (size_t)(c0 + cc) * R + r0 + rb) = o;
    }
}

// ---------------- fused 3-layer expert MLP: 4 experts x 64 rows per WG ----------------
__global__ __launch_bounds__(512, 2) void moe_fused(
    const float* __restrict__ x,            // [B][E][DIN]
    const float* __restrict__ b1,           // [E][H]
    const float* __restrict__ b2,           // [E][H]
    const float* __restrict__ b3,           // [E][DOUT]
    const unsigned short* __restrict__ W1t, // [E][H][DIN]  bf16
    const unsigned short* __restrict__ W2t, // [E][H][H]    bf16
    const unsigned short* __restrict__ W3t, // [E][DOUT][H] bf16
    float* __restrict__ out)                // [B][DOUT]  (pre-zeroed by prep)
{
    __shared__ unsigned short sMem[64 * NDIN + 2 * 64 * NH];  // 16KB X + 2x64KB H = 144KB
    unsigned short* sX  = sMem;
    unsigned short* sHA = sMem + 64 * NDIN;            // L1 output (read by L2)
    unsigned short* sHB = sHA + 64 * NH;               // L2 output (read by L3)

    const int tid  = threadIdx.x;
    const int wave = tid >> 6;
    const int lane = tid & 63;
    const int q    = lane >> 4;
    const int l16  = lane & 15;
    const int hi2  = l16 >> 2;
    const int lo2  = l16 & 3;
    const int qe   = (q ^ lo2) * 8;       // swizzled in-granule element offset

    // grid 512: xcd = lin&7; e-group = xcd>>1 (4 experts pinned per XCD pair);
    // row-tile = ((lin>>3)<<1)|(xcd&1) in 0..127.
    const int lin = blockIdx.x;
    const int xcd = lin & 7;
    const int eg  = xcd >> 1;
    const int rt  = ((lin >> 3) << 1) | (xcd & 1);
    const int b0  = rt << 6;
    const int nb  = wave * 64;

    // per-wave LDS A-frag base offsets (elements);  read addr = base + ((kt^hi2)<<5)
    int aH[4], aX[4];
#pragma unroll
    for (int m = 0; m < 4; ++m) {
        aH[m] = (m * 16 + l16) * NH   + qe;
        aX[m] = (m * 16 + l16) * NDIN + qe;
    }
    const int r0 = tid >> 4, c8 = (tid & 15) * 8;   // x staging coords

    // L3 wave mapping (constant across experts)
    const int n3 = wave & 3, mp = wave >> 2;
    int a3[2];
#pragma unroll
    for (int i = 0; i < 2; ++i) a3[i] = ((2 * mp + i) * 16 + l16) * NH + qe;

    bf16x8 bfr[3][4], afr[3][4];

    f32x4 oacc[2];
    oacc[0] = {0.f, 0.f, 0.f, 0.f}; oacc[1] = {0.f, 0.f, 0.f, 0.f};
    float bacc = 0.f;

    // ---- prologue: stage sX(e0) ----
    {
        const int e0 = eg * EG;
        const float* p0 = x + ((size_t)(b0 + r0)      * NE + e0) * NDIN + c8;
        const float* p1 = x + ((size_t)(b0 + 32 + r0) * NE + e0) * NDIN + c8;
        float4 u0 = *(const float4*)p0, u1 = *(const float4*)(p0 + 4);
        float4 u2 = *(const float4*)p1, u3 = *(const float4*)(p1 + 4);
        *(bf16x8*)&sX[shx(r0, c8)]      = cvt8(u0, u1);
        *(bf16x8*)&sX[shx(32 + r0, c8)] = cvt8(u2, u3);
    }
    __syncthreads();   // BAR-0: sX(e0) visible

#pragma unroll 1
    for (int ei = 0; ei < EG; ++ei) {
        const int e = eg * EG + ei;

        // W1 frags + b1 at iter top (L2-resident, ~300cyc, amortized over 3 GEMMs)
        const unsigned short* wb1[4];
#pragma unroll
        for (int n = 0; n < 4; ++n)
            wb1[n] = W1t + (size_t)e * NH * NDIN + (size_t)(nb + n * 16 + l16) * NDIN + q * 8;
#pragma unroll
        for (int s = 0; s < 2; ++s)
#pragma unroll
            for (int n = 0; n < 4; ++n)
                bfr[s][n] = *(const bf16x8*)(wb1[n] + s * 32);
        float4 b1q[4];
#pragma unroll
        for (int n = 0; n < 4; ++n)
            b1q[n] = *(const float4*)(b1 + e * NH + nb + n * 16 + q * 4);

        // ---------------- layer 1: acc = X @ W1 + b1, 4 kt ----------------
        f32x4 acc[4][4];
#pragma unroll
        for (int n = 0; n < 4; ++n) {
            const f32x4 bi = {b1q[n].x, b1q[n].y, b1q[n].z, b1q[n].w};
#pragma unroll
            for (int m = 0; m < 4; ++m) acc[m][n] = bi;
        }
#pragma unroll
        for (int s = 0; s < 2; ++s)
#pragma unroll
            for (int m = 0; m < 4; ++m)
                afr[s][m] = *(const bf16x8*)&sX[aX[m] + (((s ^ hi2) & 3) << 5)];

#pragma unroll
        for (int kt = 0; kt < 4; ++kt) {
            const int cur = kt % 3, pre = (kt + 2) % 3;
            if (kt < 2) {
#pragma unroll
                for (int n = 0; n < 4; ++n)
                    bfr[pre][n] = *(const bf16x8*)(wb1[n] + (kt + 2) * 32);
#pragma unroll
                for (int m = 0; m < 4; ++m)
                    afr[pre][m] = *(const bf16x8*)&sX[aX[m] + ((((kt + 2) ^ hi2) & 3) << 5)];
            }
#pragma unroll
            for (int m = 0; m < 4; ++m)
#pragma unroll
                for (int n = 0; n < 4; ++n)
                    acc[m][n] = __builtin_amdgcn_mfma_f32_16x16x32_bf16(
                        bfr[cur][n], afr[cur][m], acc[m][n], 0, 0, 0);
        }

        // W2 prologue + b2 in flight over the H1 epilogue + barrier
        const unsigned short* wb2[4];
#pragma unroll
        for (int n = 0; n < 4; ++n)
            wb2[n] = W2t + (size_t)e * NH * NH + (size_t)(nb + n * 16 + l16) * NH + q * 8;
#pragma unroll
        for (int s = 0; s < 2; ++s)
#pragma unroll
            for (int n = 0; n < 4; ++n)
                bfr[s][n] = *(const bf16x8*)(wb2[n] + s * 32);
        float4 b2q[4];
#pragma unroll
        for (int n = 0; n < 4; ++n)
            b2q[n] = *(const float4*)(b2 + e * NH + nb + n * 16 + q * 4);

        // H1 epilogue -> sHA (WAR-safe: L2(e-1) readers ended before BAR-2(e-1))
#pragma unroll
        for (int n = 0; n < 4; ++n) {
            const int c0 = nb + n * 16 + q * 4;
#pragma unroll
            for (int m = 0; m < 4; ++m) {
                bf16x4 pk;
#pragma unroll
                for (int r = 0; r < 4; ++r) pk[r] = (__bf16)fmaxf(acc[m][n][r], 0.f);
                *(bf16x4*)&sHA[shidx(m * 16 + l16, c0)] = pk;
            }
        }
        __syncthreads();   // BAR-1: sHA visible (also orders L3(e-1) before H2epi below)

        // ---------------- layer 2: acc2 = H1 @ W2 (+b2), 16 kt ----------------
        f32x4 acc2[4][4];
#pragma unroll
        for (int n = 0; n < 4; ++n) {
            const f32x4 bi = {b2q[n].x, b2q[n].y, b2q[n].z, b2q[n].w};
#pragma unroll
            for (int m = 0; m < 4; ++m) acc2[m][n] = bi;
        }
#pragma unroll
        for (int s = 0; s < 2; ++s)
#pragma unroll
            for (int m = 0; m < 4; ++m)
                afr[s][m] = *(const bf16x8*)&sHA[aH[m] + (((s ^ hi2)) << 5)];

#pragma unroll
        for (int kt = 0; kt < 16; ++kt) {
            const int cur = kt % 3, pre = (kt + 2) % 3;
            if (kt < 14) {
#pragma unroll
                for (int n = 0; n < 4; ++n)
                    bfr[pre][n] = *(const bf16x8*)(wb2[n] + (kt + 2) * 32);
#pragma unroll
                for (int m = 0; m < 4; ++m)
                    afr[pre][m] = *(const bf16x8*)&sHA[aH[m] + ((((kt + 2) ^ hi2)) << 5)];
            }
#pragma unroll
            for (int m = 0; m < 4; ++m)
#pragma unroll
                for (int n = 0; n < 4; ++n)
                    acc2[m][n] = __builtin_amdgcn_mfma_f32_16x16x32_bf16(
                        bfr[cur][n], afr[cur][m], acc2[m][n], 0, 0, 0);
        }

        // W3 first half + b3; X(e+1) -> regs (16 VGPR, held across one epilogue)
        const unsigned short* wb3 = W3t + (size_t)e * NDO * NH + (size_t)(n3 * 16 + l16) * NH + q * 8;
        bf16x8 b3f[8];
#pragma unroll
        for (int j = 0; j < 8; ++j) b3f[j] = *(const bf16x8*)(wb3 + j * 32);
        const float b3v = b3[e * NDO + n3 * 16 + l16];

        float4 xu0, xu1, xu2, xu3;
        {
            const int en = eg * EG + ((ei + 1) & (EG - 1));   // wrap: ei=3 redundant, harmless
            const float* pn0 = x + ((size_t)(b0 + r0)      * NE + en) * NDIN + c8;
            const float* pn1 = x + ((size_t)(b0 + 32 + r0) * NE + en) * NDIN + c8;
            xu0 = *(const float4*)pn0; xu1 = *(const float4*)(pn0 + 4);
            xu2 = *(const float4*)pn1; xu3 = *(const float4*)(pn1 + 4);
        }

        // H2 epilogue -> sHB (WAR-safe: L3(e-1) readers ended before BAR-1(e))
#pragma unroll
        for (int n = 0; n < 4; ++n) {
            const int c0 = nb + n * 16 + q * 4;
#pragma unroll
            for (int m = 0; m < 4; ++m) {
                bf16x4 pk;
#pragma unroll
                for (int r = 0; r < 4; ++r) pk[r] = (__bf16)fmaxf(acc2[m][n][r], 0.f);
                *(bf16x4*)&sHB[shidx(m * 16 + l16, c0)] = pk;
            }
        }
        // stage sX(e+1) (WAR-safe: L1(e) readers ended before BAR-1(e))
        *(bf16x8*)&sX[shx(r0, c8)]      = cvt8(xu0, xu1);
        *(bf16x8*)&sX[shx(32 + r0, c8)] = cvt8(xu2, xu3);
        __syncthreads();   // BAR-2: sHB + sX(e+1) visible

        // ---------------- layer 3: oacc += H2 @ W3 (b3f[8] rotating; A lookahead-3) ----------------
        bf16x8 a3f[4][2];
#pragma unroll
        for (int s = 0; s < 3; ++s)
#pragma unroll
            for (int i = 0; i < 2; ++i)
                a3f[s][i] = *(const bf16x8*)&sHB[a3[i] + (((s ^ hi2)) << 5)];

#pragma unroll
        for (int kt = 0; kt < 16; ++kt) {
            const int cur = kt & 3;
            if (kt < 13) {
                const int pre = (kt + 3) & 3;
#pragma unroll
                for (int i = 0; i < 2; ++i)
                    a3f[pre][i] = *(const bf16x8*)&sHB[a3[i] + ((((kt + 3) ^ hi2)) << 5)];
            }
#pragma unroll
            for (int i = 0; i < 2; ++i)
                oacc[i] = __builtin_amdgcn_mfma_f32_16x16x32_bf16(
                    a3f[cur][i], b3f[kt & 7], oacc[i], 0, 0, 0);
            if (kt < 8)    // rotate: slot kt&7 dead after its MFMA; load frag kt+8
                b3f[kt & 7] = *(const bf16x8*)(wb3 + (kt + 8) * 32);
        }
        bacc += b3v;
    }

    // final: 4-expert-accumulated contribution -> global fp32 atomics (1 set per block)
#pragma unroll
    for (int i = 0; i < 2; ++i) {
        const int col = n3 * 16 + l16;
#pragma unroll
        for (int r = 0; r < 4; ++r) {
            const int row = b0 + (2 * mp + i) * 16 + q * 4 + r;
            unsafeAtomicAdd(out + (size_t)row * NDO + col, oacc[i][r] + bacc);
        }
    }
}

extern "C" void kernel_launch(void* const* d_in, const int* in_sizes, int n_in,
                              void* d_out, int out_size, void* d_ws, size_t ws_size,
                              hipStream_t stream) {
    const float* x  = (const float*)d_in[0];
    const float* W1 = (const float*)d_in[1];
    const float* b1 = (const float*)d_in[2];
    const float* W2 = (const float*)d_in[3];
    const float* b2 = (const float*)d_in[4];
    const float* W3 = (const float*)d_in[5];
    const float* b3 = (const float*)d_in[6];
    float* out = (float*)d_out;

    unsigned short* W1t = (unsigned short*)d_ws;            // [E][H][DIN]
    unsigned short* W2t = W1t + (size_t)NE * NH * NDIN;     // [E][H][H]
    unsigned short* W3t = W2t + (size_t)NE * NH * NH;       // [E][DOUT][H]

    prep_weights<<<dim3(88, NE), 256, 0, stream>>>(W1, W2, W3, W1t, W2t, W3t, out);
    moe_fused<<<dim3((NB / 64) * (NE / EG)), 512, 0, stream>>>(x, b1, b2, b3, W1t, W2t, W3t, out);
}